// Round 3
// baseline (1036.395 us; speedup 1.0000x reference)
//
#include <hip/hip_runtime.h>
#include <hip/hip_bf16.h>
#include <cmath>
#include <math.h>

namespace {

constexpr int Bn = 4;
constexpr int Cn = 64;
constexpr int Wn = 64;
constexpr int Hn = 1024;
constexpr int HWn = Wn * Hn;      // 65536
constexpr int CHWn = Cn * HWn;    // 4194304

typedef float f32x4 __attribute__((ext_vector_type(4)));
typedef short bf16x8 __attribute__((ext_vector_type(8)));
union Frag { uint4 u; bf16x8 s; };

// Compile-time shift trig: zero entries fold the corresponding FMA away.
constexpr float kCA[3] = {0.9999811753f, 1.0f, 0.9999811753f};   // cos(sw*AZI)
constexpr float kSA[3] = {-0.0061358846f, 0.0f, 0.0061358846f};  // sin(sw*AZI)
constexpr float kCI[3] = {0.9999658257f, 1.0f, 0.9999658257f};   // cos(sh*INC)
constexpr float kSI[3] = {-0.0082672549f, 0.0f, 0.0082672549f};  // sin(sh*INC)

// RNE pack of two f32 -> packed bf16x2 (compiler emits v_cvt_pk_bf16_f32).
__device__ inline unsigned packbf(float a, float b) {
  union { __hip_bfloat162 h; unsigned u; } c;
  c.h = __float22bfloat162_rn(make_float2(a, b));
  return c.u;
}
__device__ inline float bflo(unsigned d) { return __uint_as_float(d << 16); }
__device__ inline float bfhi(unsigned d) { return __uint_as_float(d & 0xFFFF0000u); }

// ---------------- GroupNorm stats, stage 1: partial sums (atomic) ----------------
__global__ __launch_bounds__(256) void gn_partial_kernel(
    const float* __restrict__ x, float* __restrict__ partial) {
  const int bg = blockIdx.x >> 4, part = blockIdx.x & 15;
  const float4* base = (const float4*)(x + (size_t)bg * 2 * HWn) + part * 2048;
  float s = 0.f, s2 = 0.f;
  for (int i = threadIdx.x; i < 2048; i += 256) {
    const float4 v = base[i];
    s += v.x + v.y + v.z + v.w;
    s2 += v.x * v.x + v.y * v.y + v.z * v.z + v.w * v.w;
  }
  #pragma unroll
  for (int off = 32; off > 0; off >>= 1) {
    s  += __shfl_down(s, off, 64);
    s2 += __shfl_down(s2, off, 64);
  }
  __shared__ float red[8];
  const int wid = threadIdx.x >> 6, lid = threadIdx.x & 63;
  if (lid == 0) { red[wid * 2] = s; red[wid * 2 + 1] = s2; }
  __syncthreads();
  if (threadIdx.x == 0) {
    float ts = red[0] + red[2] + red[4] + red[6];
    float t2 = red[1] + red[3] + red[5] + red[7];
    atomicAdd(&partial[bg * 2], ts);
    atomicAdd(&partial[bg * 2 + 1], t2);
  }
}

// ---------------- GroupNorm stats, stage 2: finalize ----------------
__global__ void gn_final_kernel(const float* __restrict__ partial,
                                float* __restrict__ stats) {
  const int i = threadIdx.x;
  if (i < 128) {
    const float inv = 1.0f / (2.0f * HWn);
    const float mean = partial[2 * i] * inv;
    const float var = partial[2 * i + 1] * inv - mean * mean;
    stats[2 * i] = mean;
    stats[2 * i + 1] = rsqrtf(var + 1e-6f);
  }
}

// ------- Dual GEMM (MFMA): Y = W_a @ relu(gn(x)), Z = W_b @ relu(gn(x)) + b1 -------
// Output layout: NHWC bf16: Y[((b*64+w)*1024+h)*64 + k]
__global__ __launch_bounds__(256, 4) void dual_gemm_kernel(
    const float* __restrict__ x, const float* __restrict__ stats,
    const float* __restrict__ gw, const float* __restrict__ gb,
    const float* __restrict__ w1, const float* __restrict__ b1,
    ushort* __restrict__ Y, ushort* __restrict__ Z) {
  __shared__ float2 scsh[64];
  __shared__ float bias[64];
  __shared__ __align__(16) ushort dsY[64 * 72];
  __shared__ __align__(16) ushort dsZ[64 * 72];
  const int blk = blockIdx.x;
  const int h0 = (blk & 15) * 64;
  const int w  = (blk >> 4) & 63;
  const int b  = blk >> 10;
  const int t  = threadIdx.x;
  const int lane = t & 63, wv = t >> 6;
  const int n = lane & 15, q = lane >> 4;

  if (t < 64) {
    const int g = t >> 1;
    const float mean = stats[(b * 32 + g) * 2];
    const float rstd = stats[(b * 32 + g) * 2 + 1];
    const float sc = rstd * gw[t];
    scsh[t] = make_float2(sc, gb[t] - mean * sc);
    bias[t] = b1[t];
  }
  __syncthreads();

  // B fragments (xn), built directly in registers. n = local j col.
  const int jg = h0 + wv * 16 + n;  // global h
  const float* xb = x + (size_t)b * CHWn + (size_t)w * Hn;
  Frag Bf[2];
  #pragma unroll
  for (int kh = 0; kh < 2; kh++) {
    unsigned d[4];
    #pragma unroll
    for (int p = 0; p < 4; p++) {
      const int c0 = kh * 32 + q * 8 + p * 2;
      const float2 s0 = scsh[c0], s1 = scsh[c0 + 1];
      const float v0 = fmaxf(xb[(size_t)c0 * HWn + jg] * s0.x + s0.y, 0.f);
      const float v1 = fmaxf(xb[(size_t)(c0 + 1) * HWn + jg] * s1.x + s1.y, 0.f);
      d[p] = packbf(v0, v1);
    }
    Bf[kh].u = make_uint4(d[0], d[1], d[2], d[3]);
  }

  f32x4 accY[4], accZ[4];
  #pragma unroll
  for (int os = 0; os < 4; os++) { accY[os] = (f32x4)0.f; accZ[os] = (f32x4)0.f; }

  #pragma unroll
  for (int os = 0; os < 4; os++) {
    const int o = os * 16 + n;  // A row m = lane&15
    #pragma unroll
    for (int kh = 0; kh < 2; kh++) {
      const int k = kh * 32 + q * 8;
      const float* wra = w1 + o * 131 + k;       // W_a
      const float* wrb = w1 + o * 131 + 64 + k;  // W_b
      Frag fa, fb;
      unsigned da[4], db[4];
      #pragma unroll
      for (int p = 0; p < 4; p++) {
        da[p] = packbf(wra[2 * p], wra[2 * p + 1]);
        db[p] = packbf(wrb[2 * p], wrb[2 * p + 1]);
      }
      fa.u = make_uint4(da[0], da[1], da[2], da[3]);
      fb.u = make_uint4(db[0], db[1], db[2], db[3]);
      accY[os] = __builtin_amdgcn_mfma_f32_16x16x32_bf16(fa.s, Bf[kh].s, accY[os], 0, 0, 0);
      accZ[os] = __builtin_amdgcn_mfma_f32_16x16x32_bf16(fb.s, Bf[kh].s, accZ[os], 0, 0, 0);
    }
  }

  // D -> LDS repack: ds[j][o] (stride 72), bf16 pairs along o.
  const int jl = wv * 16 + n;
  #pragma unroll
  for (int os = 0; os < 4; os++) {
    #pragma unroll
    for (int rp = 0; rp < 4; rp += 2) {
      const int o = os * 16 + q * 4 + rp;
      *(unsigned*)&dsY[jl * 72 + o] = packbf(accY[os][rp], accY[os][rp + 1]);
      *(unsigned*)&dsZ[jl * 72 + o] =
          packbf(accZ[os][rp] + bias[o], accZ[os][rp + 1] + bias[o + 1]);
    }
  }
  __syncthreads();

  // Coalesced NHWC store
  #pragma unroll
  for (int p = 0; p < 2; p++) {
    const int slot = t + 256 * p;
    const int j = slot >> 3, og = slot & 7;
    const size_t gidx = (((size_t)b * Wn + w) * Hn + h0 + j) * 64 + og * 8;
    *(uint4*)&Y[gidx] = *(const uint4*)&dsY[j * 72 + og * 8];
    *(uint4*)&Z[gidx] = *(const uint4*)&dsZ[j * 72 + og * 8];
  }
}

// ---- 9-shift fused MFMA: out = max_s( W2 @ relu(Y_s + Z + pe_s) ) + b2 (+ x) ----
// Round-1 structure (LDS-staged Y, barrier-light, T14 issue-early/write-late,
// per-lane register B-fragments) with occupancy raised 2 -> 4 blocks/CU.
__global__ __launch_bounds__(256, 4) void shift_max_kernel(
    const ushort* __restrict__ Y, const ushort* __restrict__ Z,
    const float* __restrict__ r, const float* __restrict__ w1,
    const float* __restrict__ w2, const float* __restrict__ b2,
    const float* __restrict__ xres, const int add_res,
    float* __restrict__ out) {
  __shared__ __align__(16) ushort ys[2][66 * 72];  // [buf][jj][k], jj = h0-1..h0+64
  __shared__ float rsh[3][68];
  const int blk = blockIdx.x;
  const int h0 = (blk & 15) * 64;
  const int w  = (blk >> 4) & 63;
  const int b  = blk >> 10;
  const int t  = threadIdx.x;
  const int lane = t & 63, wv = t >> 6;
  const int n = lane & 15, q = lane >> 4;
  const int jl = wv * 16 + n;  // this lane's B column (local j)

  // r halo
  for (int i = t; i < 3 * 66; i += 256) {
    const int wi = i / 66, jj = i - wi * 66;
    const int wsrc = (w + wi - 1 + 64) & 63;
    const int hsrc = (h0 + jj - 1 + 1024) & 1023;
    rsh[wi][jj] = r[(size_t)b * HWn + wsrc * Hn + hsrc];
  }
  // stage ys buf0 for sw=-1 (wsrc = w+1)
  {
    const int wsrc = (w + 1) & 63;
    #pragma unroll
    for (int p = 0; p < 3; p++) {
      const int slot = t + 256 * p;
      if (slot < 66 * 8) {
        const int jj = slot >> 3, kg = slot & 7;
        const int hsrc = (h0 + jj - 1 + 1024) & 1023;
        *(uint4*)&ys[0][jj * 72 + kg * 8] =
            *(const uint4*)&Y[(((size_t)b * Wn + wsrc) * Hn + hsrc) * 64 + kg * 8];
      }
    }
  }

  // w2 A-fragments, resident all kernel. w2 is [o][64] fp32, 256B-aligned rows.
  Frag A[8];  // [os][kh]
  #pragma unroll
  for (int os = 0; os < 4; os++) {
    const int o = os * 16 + n;
    #pragma unroll
    for (int kh = 0; kh < 2; kh++) {
      const float4 f0 = *(const float4*)&w2[o * 64 + kh * 32 + q * 8];
      const float4 f1 = *(const float4*)&w2[o * 64 + kh * 32 + q * 8 + 4];
      A[os * 2 + kh].u = make_uint4(packbf(f0.x, f0.y), packbf(f0.z, f0.w),
                                    packbf(f1.x, f1.y), packbf(f1.z, f1.w));
    }
  }

  // pe weights for this lane's 16 k indices
  float pA0[8], pA1[8], pA2[8], pB0[8], pB1[8], pB2[8];
  #pragma unroll
  for (int i = 0; i < 8; i++) {
    const int kA = q * 8 + i, kB = 32 + q * 8 + i;
    pA0[i] = w1[kA * 131 + 128];
    pA1[i] = w1[kA * 131 + 129];
    pA2[i] = w1[kA * 131 + 130];
    pB0[i] = w1[kB * 131 + 128];
    pB1[i] = w1[kB * 131 + 129];
    pB2[i] = w1[kB * 131 + 130];
  }

  // z row (direct global, coalesced) folded with center-r term:
  // zc[k] = z[k] - rc*pw0[k]
  const float rc = r[(size_t)b * HWn + (size_t)w * Hn + h0 + jl];
  float zcA[8], zcB[8];
  {
    const size_t zbase = (((size_t)b * Wn + w) * Hn + h0 + jl) * 64;
    const uint4 z0 = *(const uint4*)&Z[zbase + q * 8];
    const uint4 z1 = *(const uint4*)&Z[zbase + 32 + q * 8];
    const unsigned zw0[4] = {z0.x, z0.y, z0.z, z0.w};
    const unsigned zw1[4] = {z1.x, z1.y, z1.z, z1.w};
    #pragma unroll
    for (int p = 0; p < 4; p++) {
      zcA[2 * p]     = bflo(zw0[p]) - rc * pA0[2 * p];
      zcA[2 * p + 1] = bfhi(zw0[p]) - rc * pA0[2 * p + 1];
      zcB[2 * p]     = bflo(zw1[p]) - rc * pB0[2 * p];
      zcB[2 * p + 1] = bfhi(zw1[p]) - rc * pB0[2 * p + 1];
    }
  }

  __syncthreads();  // rsh + ys[0] visible

  f32x4 om[4];
  #pragma unroll
  for (int os = 0; os < 4; os++) om[os] = (f32x4)(-INFINITY);

  int cur = 0;
  for (int sw = -1; sw <= 1; sw++) {
    const int isw = sw + 1;
    // T14 issue-early: next tile's global loads into registers
    uint4 g0, g1, g2;
    if (sw < 1) {
      const int wsrc = (w - (sw + 1) + 64) & 63;
      const size_t ybase = ((size_t)b * Wn + wsrc) * Hn;
      {
        const int jj = t >> 3, kg = t & 7;
        const int hsrc = (h0 + jj - 1 + 1024) & 1023;
        g0 = *(const uint4*)&Y[(ybase + hsrc) * 64 + kg * 8];
      }
      {
        const int slot = t + 256;
        const int jj = slot >> 3, kg = slot & 7;
        const int hsrc = (h0 + jj - 1 + 1024) & 1023;
        g1 = *(const uint4*)&Y[(ybase + hsrc) * 64 + kg * 8];
      }
      if (t + 512 < 66 * 8) {
        const int slot = t + 512;
        const int jj = slot >> 3, kg = slot & 7;
        const int hsrc = (h0 + jj - 1 + 1024) & 1023;
        g2 = *(const uint4*)&Y[(ybase + hsrc) * 64 + kg * 8];
      }
    }

    // 3 h-shifts, all register-resident, no barriers
    #pragma unroll
    for (int sh = -1; sh <= 1; sh++) {
      const int ish = sh + 1;
      const float m0 = kCA[isw] * kCI[ish];
      const float m1 = kCA[isw] * kSI[ish];
      const float m2 = kSA[isw];
      const float rsv = rsh[1 - sw][jl - sh + 1];
      const float a0 = rsv * m0, a1 = rsv * m1, a2 = rsv * m2;
      const int yrow = (jl - sh + 1) * 72;
      const uint4 y0 = *(const uint4*)&ys[cur][yrow + q * 8];
      const uint4 y1 = *(const uint4*)&ys[cur][yrow + 32 + q * 8];
      const unsigned yw0[4] = {y0.x, y0.y, y0.z, y0.w};
      const unsigned yw1[4] = {y1.x, y1.y, y1.z, y1.w};
      unsigned hw0[4], hw1[4];
      #pragma unroll
      for (int p = 0; p < 4; p++) {
        float hA0 = bflo(yw0[p]) + zcA[2 * p];
        hA0 = fmaf(a0, pA0[2 * p], hA0);
        if (kSI[ish] != 0.f) hA0 = fmaf(a1, pA1[2 * p], hA0);
        if (kSA[isw] != 0.f) hA0 = fmaf(a2, pA2[2 * p], hA0);
        float hA1 = bfhi(yw0[p]) + zcA[2 * p + 1];
        hA1 = fmaf(a0, pA0[2 * p + 1], hA1);
        if (kSI[ish] != 0.f) hA1 = fmaf(a1, pA1[2 * p + 1], hA1);
        if (kSA[isw] != 0.f) hA1 = fmaf(a2, pA2[2 * p + 1], hA1);
        hw0[p] = packbf(fmaxf(hA0, 0.f), fmaxf(hA1, 0.f));
        float hB0 = bflo(yw1[p]) + zcB[2 * p];
        hB0 = fmaf(a0, pB0[2 * p], hB0);
        if (kSI[ish] != 0.f) hB0 = fmaf(a1, pB1[2 * p], hB0);
        if (kSA[isw] != 0.f) hB0 = fmaf(a2, pB2[2 * p], hB0);
        float hB1 = bfhi(yw1[p]) + zcB[2 * p + 1];
        hB1 = fmaf(a0, pB0[2 * p + 1], hB1);
        if (kSI[ish] != 0.f) hB1 = fmaf(a1, pB1[2 * p + 1], hB1);
        if (kSA[isw] != 0.f) hB1 = fmaf(a2, pB2[2 * p + 1], hB1);
        hw1[p] = packbf(fmaxf(hB0, 0.f), fmaxf(hB1, 0.f));
      }
      Frag Bf0, Bf1;
      Bf0.u = make_uint4(hw0[0], hw0[1], hw0[2], hw0[3]);
      Bf1.u = make_uint4(hw1[0], hw1[1], hw1[2], hw1[3]);
      #pragma unroll
      for (int os = 0; os < 4; os++) {
        f32x4 acc = (f32x4)0.f;
        acc = __builtin_amdgcn_mfma_f32_16x16x32_bf16(A[os * 2].s, Bf0.s, acc, 0, 0, 0);
        acc = __builtin_amdgcn_mfma_f32_16x16x32_bf16(A[os * 2 + 1].s, Bf1.s, acc, 0, 0, 0);
        #pragma unroll
        for (int e = 0; e < 4; e++) om[os][e] = fmaxf(om[os][e], acc[e]);
      }
    }

    // T14 write-late: park the prefetched tile in the other buffer
    if (sw < 1) {
      {
        const int jj = t >> 3, kg = t & 7;
        *(uint4*)&ys[cur ^ 1][jj * 72 + kg * 8] = g0;
      }
      {
        const int slot = t + 256;
        const int jj = slot >> 3, kg = slot & 7;
        *(uint4*)&ys[cur ^ 1][jj * 72 + kg * 8] = g1;
      }
      if (t + 512 < 66 * 8) {
        const int slot = t + 512;
        const int jj = slot >> 3, kg = slot & 7;
        *(uint4*)&ys[cur ^ 1][jj * 72 + kg * 8] = g2;
      }
    }
    __syncthreads();  // staging complete AND all readers of ys[cur] done
    cur ^= 1;
  }

  // epilogue: D layout col=lane&15 (j), row=q*4+e (o)
  const int jgl = h0 + jl;
  #pragma unroll
  for (int os = 0; os < 4; os++) {
    #pragma unroll
    for (int e = 0; e < 4; e++) {
      const int o = os * 16 + q * 4 + e;
      const size_t idx = ((size_t)b * Cn + o) * HWn + (size_t)w * Hn + jgl;
      float v = om[os][e] + b2[o];
      if (add_res) v += xres[idx];
      out[idx] = v;
    }
  }
}

}  // namespace

extern "C" void kernel_launch(void* const* d_in, const int* in_sizes, int n_in,
                              void* d_out, int out_size, void* d_ws, size_t ws_size,
                              hipStream_t stream) {
  const float* x    = (const float*)d_in[0];
  const float* r    = (const float*)d_in[1];
  const float* n1w  = (const float*)d_in[2];
  const float* n1b  = (const float*)d_in[3];
  const float* c1w1 = (const float*)d_in[4];
  const float* c1b1 = (const float*)d_in[5];
  const float* c1w2 = (const float*)d_in[6];
  const float* c1b2 = (const float*)d_in[7];
  const float* n2w  = (const float*)d_in[8];
  const float* n2b  = (const float*)d_in[9];
  const float* c2w1 = (const float*)d_in[10];
  const float* c2b1 = (const float*)d_in[11];
  const float* c2w2 = (const float*)d_in[12];
  const float* c2b2 = (const float*)d_in[13];
  float* out = (float*)d_out;

  // ws: [partial 256f][stats 256f][pad to 4096B][Y bf16 32MiB][Z bf16 32MiB]
  float* partial = (float*)d_ws;
  float* statsf  = partial + 256;
  ushort* Ybf = (ushort*)((char*)d_ws + 4096);
  ushort* Zbf = Ybf + (size_t)Bn * Wn * Hn * 64;

  // ---- block 1 ----
  hipMemsetAsync(partial, 0, 256 * sizeof(float), stream);
  gn_partial_kernel<<<2048, 256, 0, stream>>>(x, partial);
  gn_final_kernel<<<1, 128, 0, stream>>>(partial, statsf);
  dual_gemm_kernel<<<4096, 256, 0, stream>>>(x, statsf, n1w, n1b, c1w1, c1b1, Ybf, Zbf);
  shift_max_kernel<<<4096, 256, 0, stream>>>(Ybf, Zbf, r, c1w1, c1w2, c1b2, x, 0, out);
  // ---- block 2 (edge_conv1 result parked in d_out) ----
  hipMemsetAsync(partial, 0, 256 * sizeof(float), stream);
  gn_partial_kernel<<<2048, 256, 0, stream>>>(out, partial);
  gn_final_kernel<<<1, 128, 0, stream>>>(partial, statsf);
  dual_gemm_kernel<<<4096, 256, 0, stream>>>(out, statsf, n2w, n2b, c2w1, c2b1, Ybf, Zbf);
  shift_max_kernel<<<4096, 256, 0, stream>>>(Ybf, Zbf, r, c2w1, c2w2, c2b2, x, 1, out);
}

// Round 4
// 496.879 us; speedup vs baseline: 2.0858x; 2.0858x over previous
//
#include <hip/hip_runtime.h>
#include <hip/hip_bf16.h>
#include <cmath>
#include <math.h>

namespace {

constexpr int Bn = 4;
constexpr int Cn = 64;
constexpr int Wn = 64;
constexpr int Hn = 1024;
constexpr int HWn = Wn * Hn;      // 65536
constexpr int CHWn = Cn * HWn;    // 4194304

typedef float f32x4 __attribute__((ext_vector_type(4)));
typedef short bf16x8 __attribute__((ext_vector_type(8)));
union Frag { uint4 u; bf16x8 s; };

// Compile-time shift trig: zero entries fold the corresponding FMA away.
constexpr float kCA[3] = {0.9999811753f, 1.0f, 0.9999811753f};   // cos(sw*AZI)
constexpr float kSA[3] = {-0.0061358846f, 0.0f, 0.0061358846f};  // sin(sw*AZI)
constexpr float kCI[3] = {0.9999658257f, 1.0f, 0.9999658257f};   // cos(sh*INC)
constexpr float kSI[3] = {-0.0082672549f, 0.0f, 0.0082672549f};  // sin(sh*INC)

// RNE pack of two f32 -> packed bf16x2 (compiler emits v_cvt_pk_bf16_f32).
__device__ inline unsigned packbf(float a, float b) {
  union { __hip_bfloat162 h; unsigned u; } c;
  c.h = __float22bfloat162_rn(make_float2(a, b));
  return c.u;
}
__device__ inline float bflo(unsigned d) { return __uint_as_float(d << 16); }
__device__ inline float bfhi(unsigned d) { return __uint_as_float(d & 0xFFFF0000u); }

// ---------------- GroupNorm stats, stage 1: partial sums (atomic) ----------------
__global__ __launch_bounds__(256) void gn_partial_kernel(
    const float* __restrict__ x, float* __restrict__ partial) {
  const int bg = blockIdx.x >> 4, part = blockIdx.x & 15;
  const float4* base = (const float4*)(x + (size_t)bg * 2 * HWn) + part * 2048;
  float s = 0.f, s2 = 0.f;
  for (int i = threadIdx.x; i < 2048; i += 256) {
    const float4 v = base[i];
    s += v.x + v.y + v.z + v.w;
    s2 += v.x * v.x + v.y * v.y + v.z * v.z + v.w * v.w;
  }
  #pragma unroll
  for (int off = 32; off > 0; off >>= 1) {
    s  += __shfl_down(s, off, 64);
    s2 += __shfl_down(s2, off, 64);
  }
  __shared__ float red[8];
  const int wid = threadIdx.x >> 6, lid = threadIdx.x & 63;
  if (lid == 0) { red[wid * 2] = s; red[wid * 2 + 1] = s2; }
  __syncthreads();
  if (threadIdx.x == 0) {
    float ts = red[0] + red[2] + red[4] + red[6];
    float t2 = red[1] + red[3] + red[5] + red[7];
    atomicAdd(&partial[bg * 2], ts);
    atomicAdd(&partial[bg * 2 + 1], t2);
  }
}

// ---------------- GroupNorm stats, stage 2: finalize ----------------
__global__ void gn_final_kernel(const float* __restrict__ partial,
                                float* __restrict__ stats) {
  const int i = threadIdx.x;
  if (i < 128) {
    const float inv = 1.0f / (2.0f * HWn);
    const float mean = partial[2 * i] * inv;
    const float var = partial[2 * i + 1] * inv - mean * mean;
    stats[2 * i] = mean;
    stats[2 * i + 1] = rsqrtf(var + 1e-6f);
  }
}

// --------- Weight pre-pack: w1 -> bf16 [o][k] tables (a|b), w2 -> bf16, pe f32x4 ---------
__global__ void pack_weights_kernel(const float* __restrict__ w1,
                                    const float* __restrict__ w2,
                                    ushort* __restrict__ w1a, ushort* __restrict__ w1b,
                                    ushort* __restrict__ w2p, float* __restrict__ pe) {
  const int t = threadIdx.x;  // 256 threads
  for (int i = t; i < 64 * 32; i += 256) {  // one bf16 pair per iter
    const int o = i >> 5, kp = (i & 31) * 2;
    *(unsigned*)&w1a[o * 64 + kp] = packbf(w1[o * 131 + kp], w1[o * 131 + kp + 1]);
    *(unsigned*)&w1b[o * 64 + kp] = packbf(w1[o * 131 + 64 + kp], w1[o * 131 + 64 + kp + 1]);
    *(unsigned*)&w2p[o * 64 + kp] = packbf(w2[o * 64 + kp], w2[o * 64 + kp + 1]);
  }
  if (t < 64) {
    pe[t * 4 + 0] = w1[t * 131 + 128];
    pe[t * 4 + 1] = w1[t * 131 + 129];
    pe[t * 4 + 2] = w1[t * 131 + 130];
    pe[t * 4 + 3] = 0.f;
  }
}

// ------- Dual GEMM (MFMA): Y = W_a @ relu(gn(x)), Z = W_b @ relu(gn(x)) + b1 -------
// Output layout: NHWC bf16: Y[((b*64+w)*1024+h)*64 + k]
__global__ __launch_bounds__(256, 2) void dual_gemm_kernel(
    const float* __restrict__ x, const float* __restrict__ stats,
    const float* __restrict__ gw, const float* __restrict__ gb,
    const ushort* __restrict__ w1a, const ushort* __restrict__ w1b,
    const float* __restrict__ b1,
    ushort* __restrict__ Y, ushort* __restrict__ Z) {
  __shared__ float2 scsh[64];
  __shared__ float bias[64];
  __shared__ __align__(16) ushort dsY[64 * 72];
  __shared__ __align__(16) ushort dsZ[64 * 72];
  const int blk = blockIdx.x;
  const int h0 = (blk & 15) * 64;
  const int w  = (blk >> 4) & 63;
  const int b  = blk >> 10;
  const int t  = threadIdx.x;
  const int lane = t & 63, wv = t >> 6;
  const int n = lane & 15, q = lane >> 4;

  if (t < 64) {
    const int g = t >> 1;
    const float mean = stats[(b * 32 + g) * 2];
    const float rstd = stats[(b * 32 + g) * 2 + 1];
    const float sc = rstd * gw[t];
    scsh[t] = make_float2(sc, gb[t] - mean * sc);
    bias[t] = b1[t];
  }
  __syncthreads();

  // B fragments (xn), built directly in registers. n = local j col.
  const int jg = h0 + wv * 16 + n;  // global h
  const float* xb = x + (size_t)b * CHWn + (size_t)w * Hn;
  Frag Bf[2];
  #pragma unroll
  for (int kh = 0; kh < 2; kh++) {
    unsigned d[4];
    #pragma unroll
    for (int p = 0; p < 4; p++) {
      const int c0 = kh * 32 + q * 8 + p * 2;
      const float2 s0 = scsh[c0], s1 = scsh[c0 + 1];
      const float v0 = fmaxf(xb[(size_t)c0 * HWn + jg] * s0.x + s0.y, 0.f);
      const float v1 = fmaxf(xb[(size_t)(c0 + 1) * HWn + jg] * s1.x + s1.y, 0.f);
      d[p] = packbf(v0, v1);
    }
    Bf[kh].u = make_uint4(d[0], d[1], d[2], d[3]);
  }

  f32x4 accY[4], accZ[4];
  #pragma unroll
  for (int os = 0; os < 4; os++) { accY[os] = (f32x4)0.f; accZ[os] = (f32x4)0.f; }

  #pragma unroll
  for (int os = 0; os < 4; os++) {
    const int o = os * 16 + n;  // A row m = lane&15
    #pragma unroll
    for (int kh = 0; kh < 2; kh++) {
      const int k = kh * 32 + q * 8;
      Frag fa, fb;
      fa.u = *(const uint4*)&w1a[o * 64 + k];  // pre-packed bf16, 16B aligned
      fb.u = *(const uint4*)&w1b[o * 64 + k];
      accY[os] = __builtin_amdgcn_mfma_f32_16x16x32_bf16(fa.s, Bf[kh].s, accY[os], 0, 0, 0);
      accZ[os] = __builtin_amdgcn_mfma_f32_16x16x32_bf16(fb.s, Bf[kh].s, accZ[os], 0, 0, 0);
    }
  }

  // D -> LDS repack: ds[j][o] (stride 72), bf16 pairs along o.
  const int jl = wv * 16 + n;
  #pragma unroll
  for (int os = 0; os < 4; os++) {
    #pragma unroll
    for (int rp = 0; rp < 4; rp += 2) {
      const int o = os * 16 + q * 4 + rp;
      *(unsigned*)&dsY[jl * 72 + o] = packbf(accY[os][rp], accY[os][rp + 1]);
      *(unsigned*)&dsZ[jl * 72 + o] =
          packbf(accZ[os][rp] + bias[o], accZ[os][rp + 1] + bias[o + 1]);
    }
  }
  __syncthreads();

  // Coalesced NHWC store
  #pragma unroll
  for (int p = 0; p < 2; p++) {
    const int slot = t + 256 * p;
    const int j = slot >> 3, og = slot & 7;
    const size_t gidx = (((size_t)b * Wn + w) * Hn + h0 + j) * 64 + og * 8;
    *(uint4*)&Y[gidx] = *(const uint4*)&dsY[j * 72 + og * 8];
    *(uint4*)&Z[gidx] = *(const uint4*)&dsZ[j * 72 + og * 8];
  }
}

// ---- 9-shift fused MFMA: out = max_s( W2 @ relu(Y_s + Z + pe_s) ) + b2 (+ x) ----
// All 3 Y w-columns staged in one up-front burst (max memory-level
// parallelism: ~9 outstanding uint4 loads/thread), then ONE barrier and a
// fully-unrolled 9-shift compute with zero further synchronization.
__global__ __launch_bounds__(256, 2) void shift_max_kernel(
    const ushort* __restrict__ Y, const ushort* __restrict__ Z,
    const float* __restrict__ r, const float* __restrict__ pe,
    const ushort* __restrict__ w2p, const float* __restrict__ b2,
    const float* __restrict__ xres, const int add_res,
    float* __restrict__ out) {
  __shared__ __align__(16) ushort ys3[3][66 * 72];  // [wi][jj][k], wi: wsrc=w+wi-1
  __shared__ float rsh[3][68];
  const int blk = blockIdx.x;
  const int h0 = (blk & 15) * 64;
  const int w  = (blk >> 4) & 63;
  const int b  = blk >> 10;
  const int t  = threadIdx.x;
  const int lane = t & 63, wv = t >> 6;
  const int n = lane & 15, q = lane >> 4;
  const int jl = wv * 16 + n;  // this lane's B column (local j)

  // ---- staging burst: issue ALL Y-halo loads first (phase 1), then write (phase 2)
  uint4 g[3][3];
  #pragma unroll
  for (int wi = 0; wi < 3; wi++) {
    const int wsrc = (w + wi - 1 + 64) & 63;
    const size_t ybase = ((size_t)b * Wn + wsrc) * Hn;
    #pragma unroll
    for (int p = 0; p < 3; p++) {
      const int slot = t + 256 * p;
      if (slot < 66 * 8) {
        const int jj = slot >> 3, kg = slot & 7;
        const int hsrc = (h0 + jj - 1 + 1024) & 1023;
        g[wi][p] = *(const uint4*)&Y[(ybase + hsrc) * 64 + kg * 8];
      }
    }
  }
  // r halo
  for (int i = t; i < 3 * 66; i += 256) {
    const int wi = i / 66, jj = i - wi * 66;
    const int wsrc = (w + wi - 1 + 64) & 63;
    const int hsrc = (h0 + jj - 1 + 1024) & 1023;
    rsh[wi][jj] = r[(size_t)b * HWn + wsrc * Hn + hsrc];
  }
  #pragma unroll
  for (int wi = 0; wi < 3; wi++) {
    #pragma unroll
    for (int p = 0; p < 3; p++) {
      const int slot = t + 256 * p;
      if (slot < 66 * 8) {
        const int jj = slot >> 3, kg = slot & 7;
        *(uint4*)&ys3[wi][jj * 72 + kg * 8] = g[wi][p];
      }
    }
  }

  // w2 A-fragments from pre-packed bf16 table (L2-hot, 8 x uint4).
  Frag A[8];  // [os][kh]
  #pragma unroll
  for (int os = 0; os < 4; os++) {
    const int o = os * 16 + n;
    #pragma unroll
    for (int kh = 0; kh < 2; kh++)
      A[os * 2 + kh].u = *(const uint4*)&w2p[o * 64 + kh * 32 + q * 8];
  }

  // pe weights for this lane's 16 k indices (vector loads from packed table)
  float pA0[8], pA1[8], pA2[8], pB0[8], pB1[8], pB2[8];
  #pragma unroll
  for (int i = 0; i < 8; i++) {
    const float4 va = *(const float4*)&pe[(q * 8 + i) * 4];
    const float4 vb = *(const float4*)&pe[(32 + q * 8 + i) * 4];
    pA0[i] = va.x; pA1[i] = va.y; pA2[i] = va.z;
    pB0[i] = vb.x; pB1[i] = vb.y; pB2[i] = vb.z;
  }

  // z row (direct global, coalesced) folded with center-r term:
  // zc[k] = z[k] - rc*pw0[k]
  const float rc = r[(size_t)b * HWn + (size_t)w * Hn + h0 + jl];
  float zcA[8], zcB[8];
  {
    const size_t zbase = (((size_t)b * Wn + w) * Hn + h0 + jl) * 64;
    const uint4 z0 = *(const uint4*)&Z[zbase + q * 8];
    const uint4 z1 = *(const uint4*)&Z[zbase + 32 + q * 8];
    const unsigned zw0[4] = {z0.x, z0.y, z0.z, z0.w};
    const unsigned zw1[4] = {z1.x, z1.y, z1.z, z1.w};
    #pragma unroll
    for (int p = 0; p < 4; p++) {
      zcA[2 * p]     = bflo(zw0[p]) - rc * pA0[2 * p];
      zcA[2 * p + 1] = bfhi(zw0[p]) - rc * pA0[2 * p + 1];
      zcB[2 * p]     = bflo(zw1[p]) - rc * pB0[2 * p];
      zcB[2 * p + 1] = bfhi(zw1[p]) - rc * pB0[2 * p + 1];
    }
  }

  __syncthreads();  // all staging visible; no further barriers

  f32x4 om[4];
  #pragma unroll
  for (int os = 0; os < 4; os++) om[os] = (f32x4)(-INFINITY);

  #pragma unroll
  for (int sw = -1; sw <= 1; sw++) {
    const int isw = sw + 1;
    const ushort* ysb = ys3[1 - sw];  // wsrc = w - sw
    #pragma unroll
    for (int sh = -1; sh <= 1; sh++) {
      const int ish = sh + 1;
      const float m0 = kCA[isw] * kCI[ish];
      const float m1 = kCA[isw] * kSI[ish];
      const float m2 = kSA[isw];
      const float rsv = rsh[1 - sw][jl - sh + 1];
      const float a0 = rsv * m0, a1 = rsv * m1, a2 = rsv * m2;
      const int yrow = (jl - sh + 1) * 72;
      const uint4 y0 = *(const uint4*)&ysb[yrow + q * 8];
      const uint4 y1 = *(const uint4*)&ysb[yrow + 32 + q * 8];
      const unsigned yw0[4] = {y0.x, y0.y, y0.z, y0.w};
      const unsigned yw1[4] = {y1.x, y1.y, y1.z, y1.w};
      unsigned hw0[4], hw1[4];
      #pragma unroll
      for (int p = 0; p < 4; p++) {
        float hA0 = bflo(yw0[p]) + zcA[2 * p];
        hA0 = fmaf(a0, pA0[2 * p], hA0);
        if (kSI[ish] != 0.f) hA0 = fmaf(a1, pA1[2 * p], hA0);
        if (kSA[isw] != 0.f) hA0 = fmaf(a2, pA2[2 * p], hA0);
        float hA1 = bfhi(yw0[p]) + zcA[2 * p + 1];
        hA1 = fmaf(a0, pA0[2 * p + 1], hA1);
        if (kSI[ish] != 0.f) hA1 = fmaf(a1, pA1[2 * p + 1], hA1);
        if (kSA[isw] != 0.f) hA1 = fmaf(a2, pA2[2 * p + 1], hA1);
        hw0[p] = packbf(fmaxf(hA0, 0.f), fmaxf(hA1, 0.f));
        float hB0 = bflo(yw1[p]) + zcB[2 * p];
        hB0 = fmaf(a0, pB0[2 * p], hB0);
        if (kSI[ish] != 0.f) hB0 = fmaf(a1, pB1[2 * p], hB0);
        if (kSA[isw] != 0.f) hB0 = fmaf(a2, pB2[2 * p], hB0);
        float hB1 = bfhi(yw1[p]) + zcB[2 * p + 1];
        hB1 = fmaf(a0, pB0[2 * p + 1], hB1);
        if (kSI[ish] != 0.f) hB1 = fmaf(a1, pB1[2 * p + 1], hB1);
        if (kSA[isw] != 0.f) hB1 = fmaf(a2, pB2[2 * p + 1], hB1);
        hw1[p] = packbf(fmaxf(hB0, 0.f), fmaxf(hB1, 0.f));
      }
      Frag Bf0, Bf1;
      Bf0.u = make_uint4(hw0[0], hw0[1], hw0[2], hw0[3]);
      Bf1.u = make_uint4(hw1[0], hw1[1], hw1[2], hw1[3]);
      #pragma unroll
      for (int os = 0; os < 4; os++) {
        f32x4 acc = (f32x4)0.f;
        acc = __builtin_amdgcn_mfma_f32_16x16x32_bf16(A[os * 2].s, Bf0.s, acc, 0, 0, 0);
        acc = __builtin_amdgcn_mfma_f32_16x16x32_bf16(A[os * 2 + 1].s, Bf1.s, acc, 0, 0, 0);
        #pragma unroll
        for (int e = 0; e < 4; e++) om[os][e] = fmaxf(om[os][e], acc[e]);
      }
    }
  }

  // epilogue: D layout col=lane&15 (j), row=q*4+e (o)
  const int jgl = h0 + jl;
  #pragma unroll
  for (int os = 0; os < 4; os++) {
    #pragma unroll
    for (int e = 0; e < 4; e++) {
      const int o = os * 16 + q * 4 + e;
      const size_t idx = ((size_t)b * Cn + o) * HWn + (size_t)w * Hn + jgl;
      float v = om[os][e] + b2[o];
      if (add_res) v += xres[idx];
      out[idx] = v;
    }
  }
}

}  // namespace

extern "C" void kernel_launch(void* const* d_in, const int* in_sizes, int n_in,
                              void* d_out, int out_size, void* d_ws, size_t ws_size,
                              hipStream_t stream) {
  const float* x    = (const float*)d_in[0];
  const float* r    = (const float*)d_in[1];
  const float* n1w  = (const float*)d_in[2];
  const float* n1b  = (const float*)d_in[3];
  const float* c1w1 = (const float*)d_in[4];
  const float* c1b1 = (const float*)d_in[5];
  const float* c1w2 = (const float*)d_in[6];
  const float* c1b2 = (const float*)d_in[7];
  const float* n2w  = (const float*)d_in[8];
  const float* n2b  = (const float*)d_in[9];
  const float* c2w1 = (const float*)d_in[10];
  const float* c2b1 = (const float*)d_in[11];
  const float* c2w2 = (const float*)d_in[12];
  const float* c2b2 = (const float*)d_in[13];
  float* out = (float*)d_out;

  // ws: [partial 256f][stats 256f][pe 256f][pad to 4096B]
  //     [Y bf16 32MiB][Z bf16 32MiB][w1a 8K][w1b 8K][w2p 8K]
  float* partial = (float*)d_ws;
  float* statsf  = partial + 256;
  float* pe      = partial + 512;
  ushort* Ybf = (ushort*)((char*)d_ws + 4096);
  ushort* Zbf = Ybf + (size_t)Bn * Wn * Hn * 64;
  ushort* w1a = Zbf + (size_t)Bn * Wn * Hn * 64;
  ushort* w1b = w1a + 64 * 64;
  ushort* w2p = w1b + 64 * 64;

  // ---- block 1 ----
  hipMemsetAsync(partial, 0, 256 * sizeof(float), stream);
  gn_partial_kernel<<<2048, 256, 0, stream>>>(x, partial);
  gn_final_kernel<<<1, 128, 0, stream>>>(partial, statsf);
  pack_weights_kernel<<<1, 256, 0, stream>>>(c1w1, c1w2, w1a, w1b, w2p, pe);
  dual_gemm_kernel<<<4096, 256, 0, stream>>>(x, statsf, n1w, n1b, w1a, w1b, c1b1, Ybf, Zbf);
  shift_max_kernel<<<4096, 256, 0, stream>>>(Ybf, Zbf, r, pe, w2p, c1b2, x, 0, out);
  // ---- block 2 (edge_conv1 result parked in d_out) ----
  hipMemsetAsync(partial, 0, 256 * sizeof(float), stream);
  gn_partial_kernel<<<2048, 256, 0, stream>>>(out, partial);
  gn_final_kernel<<<1, 128, 0, stream>>>(partial, statsf);
  pack_weights_kernel<<<1, 256, 0, stream>>>(c2w1, c2w2, w1a, w1b, w2p, pe);
  dual_gemm_kernel<<<4096, 256, 0, stream>>>(out, statsf, n2w, n2b, w1a, w1b, c2b1, Ybf, Zbf);
  shift_max_kernel<<<4096, 256, 0, stream>>>(Ybf, Zbf, r, pe, w2p, c2b2, x, 1, out);
}

// Round 5
// 437.499 us; speedup vs baseline: 2.3689x; 1.1357x over previous
//
#include <hip/hip_runtime.h>
#include <hip/hip_bf16.h>
#include <cmath>
#include <math.h>

namespace {

constexpr int Bn = 4;
constexpr int Cn = 64;
constexpr int Wn = 64;
constexpr int Hn = 1024;
constexpr int HWn = Wn * Hn;      // 65536
constexpr int CHWn = Cn * HWn;    // 4194304

typedef float f32x4 __attribute__((ext_vector_type(4)));
typedef short bf16x8 __attribute__((ext_vector_type(8)));
union Frag { uint4 u; bf16x8 s; };

// Compile-time shift trig (index 0..2 = shift -1..+1).
constexpr float kCA[3] = {0.9999811753f, 1.0f, 0.9999811753f};   // cos(sw*AZI)
constexpr float kSA[3] = {-0.0061358846f, 0.0f, 0.0061358846f};  // sin(sw*AZI)
constexpr float kCI[3] = {0.9999658257f, 1.0f, 0.9999658257f};   // cos(sh*INC)
constexpr float kSI[3] = {-0.0082672549f, 0.0f, 0.0082672549f};  // sin(sh*INC)

// RNE pack of two f32 -> packed bf16x2 (compiler emits v_cvt_pk_bf16_f32).
__device__ inline unsigned packbf(float a, float b) {
  union { __hip_bfloat162 h; unsigned u; } c;
  c.h = __float22bfloat162_rn(make_float2(a, b));
  return c.u;
}
__device__ inline float bflo(unsigned d) { return __uint_as_float(d << 16); }
__device__ inline float bfhi(unsigned d) { return __uint_as_float(d & 0xFFFF0000u); }

// ---------------- GroupNorm stats, stage 1: partial sums (atomic) ----------------
__global__ __launch_bounds__(256) void gn_partial_kernel(
    const float* __restrict__ x, float* __restrict__ partial) {
  const int bg = blockIdx.x >> 4, part = blockIdx.x & 15;
  const float4* base = (const float4*)(x + (size_t)bg * 2 * HWn) + part * 2048;
  float s = 0.f, s2 = 0.f;
  for (int i = threadIdx.x; i < 2048; i += 256) {
    const float4 v = base[i];
    s += v.x + v.y + v.z + v.w;
    s2 += v.x * v.x + v.y * v.y + v.z * v.z + v.w * v.w;
  }
  #pragma unroll
  for (int off = 32; off > 0; off >>= 1) {
    s  += __shfl_down(s, off, 64);
    s2 += __shfl_down(s2, off, 64);
  }
  __shared__ float red[8];
  const int wid = threadIdx.x >> 6, lid = threadIdx.x & 63;
  if (lid == 0) { red[wid * 2] = s; red[wid * 2 + 1] = s2; }
  __syncthreads();
  if (threadIdx.x == 0) {
    float ts = red[0] + red[2] + red[4] + red[6];
    float t2 = red[1] + red[3] + red[5] + red[7];
    atomicAdd(&partial[bg * 2], ts);
    atomicAdd(&partial[bg * 2 + 1], t2);
  }
}

// ---------------- GroupNorm stats, stage 2: finalize ----------------
__global__ void gn_final_kernel(const float* __restrict__ partial,
                                float* __restrict__ stats) {
  const int i = threadIdx.x;
  if (i < 128) {
    const float inv = 1.0f / (2.0f * HWn);
    const float mean = partial[2 * i] * inv;
    const float var = partial[2 * i + 1] * inv - mean * mean;
    stats[2 * i] = mean;
    stats[2 * i + 1] = rsqrtf(var + 1e-6f);
  }
}

// --------- Weight pre-pack: w1/w2 -> bf16 tables, vs9[9][64] shift table, pw0 ---------
__global__ void pack_weights_kernel(const float* __restrict__ w1,
                                    const float* __restrict__ w2,
                                    ushort* __restrict__ w1a, ushort* __restrict__ w1b,
                                    ushort* __restrict__ w2p,
                                    float* __restrict__ vs9, float* __restrict__ pw0) {
  const int t = threadIdx.x;  // 256 threads
  for (int i = t; i < 64 * 32; i += 256) {  // one bf16 pair per iter
    const int o = i >> 5, kp = (i & 31) * 2;
    *(unsigned*)&w1a[o * 64 + kp] = packbf(w1[o * 131 + kp], w1[o * 131 + kp + 1]);
    *(unsigned*)&w1b[o * 64 + kp] = packbf(w1[o * 131 + 64 + kp], w1[o * 131 + 64 + kp + 1]);
    *(unsigned*)&w2p[o * 64 + kp] = packbf(w2[o * 64 + kp], w2[o * 64 + kp + 1]);
  }
  if (t < 64) pw0[t] = w1[t * 131 + 128];
  // vs_s[k] = m0*pw0[k] + m1*pw1[k] + m2*pw2[k], s = isw*3+ish (isw,ish in 0..2)
  for (int i = t; i < 9 * 64; i += 256) {
    const int s = i >> 6, k = i & 63;
    const int isw = s / 3, ish = s % 3;
    const float m0 = kCA[isw] * kCI[ish];
    const float m1 = kCA[isw] * kSI[ish];
    const float m2 = kSA[isw];
    vs9[s * 64 + k] = m0 * w1[k * 131 + 128] + m1 * w1[k * 131 + 129] +
                      m2 * w1[k * 131 + 130];
  }
}

// ------- Dual GEMM (MFMA): Y = W_a @ relu(gn(x)), Z = W_b @ relu(gn(x)) + b1 -------
// Output layout: NHWC bf16: Y[((b*64+w)*1024+h)*64 + k]
__global__ __launch_bounds__(256, 2) void dual_gemm_kernel(
    const float* __restrict__ x, const float* __restrict__ stats,
    const float* __restrict__ gw, const float* __restrict__ gb,
    const ushort* __restrict__ w1a, const ushort* __restrict__ w1b,
    const float* __restrict__ b1,
    ushort* __restrict__ Y, ushort* __restrict__ Z) {
  __shared__ float2 scsh[64];
  __shared__ float bias[64];
  __shared__ __align__(16) ushort dsY[64 * 72];
  __shared__ __align__(16) ushort dsZ[64 * 72];
  const int blk = blockIdx.x;
  const int h0 = (blk & 15) * 64;
  const int w  = (blk >> 4) & 63;
  const int b  = blk >> 10;
  const int t  = threadIdx.x;
  const int lane = t & 63, wv = t >> 6;
  const int n = lane & 15, q = lane >> 4;

  if (t < 64) {
    const int g = t >> 1;
    const float mean = stats[(b * 32 + g) * 2];
    const float rstd = stats[(b * 32 + g) * 2 + 1];
    const float sc = rstd * gw[t];
    scsh[t] = make_float2(sc, gb[t] - mean * sc);
    bias[t] = b1[t];
  }
  __syncthreads();

  // B fragments (xn), built directly in registers. n = local j col.
  const int jg = h0 + wv * 16 + n;  // global h
  const float* xb = x + (size_t)b * CHWn + (size_t)w * Hn;
  Frag Bf[2];
  #pragma unroll
  for (int kh = 0; kh < 2; kh++) {
    unsigned d[4];
    #pragma unroll
    for (int p = 0; p < 4; p++) {
      const int c0 = kh * 32 + q * 8 + p * 2;
      const float2 s0 = scsh[c0], s1 = scsh[c0 + 1];
      const float v0 = fmaxf(xb[(size_t)c0 * HWn + jg] * s0.x + s0.y, 0.f);
      const float v1 = fmaxf(xb[(size_t)(c0 + 1) * HWn + jg] * s1.x + s1.y, 0.f);
      d[p] = packbf(v0, v1);
    }
    Bf[kh].u = make_uint4(d[0], d[1], d[2], d[3]);
  }

  f32x4 accY[4], accZ[4];
  #pragma unroll
  for (int os = 0; os < 4; os++) { accY[os] = (f32x4)0.f; accZ[os] = (f32x4)0.f; }

  #pragma unroll
  for (int os = 0; os < 4; os++) {
    const int o = os * 16 + n;  // A row m = lane&15
    #pragma unroll
    for (int kh = 0; kh < 2; kh++) {
      const int k = kh * 32 + q * 8;
      Frag fa, fb;
      fa.u = *(const uint4*)&w1a[o * 64 + k];  // pre-packed bf16, 16B aligned
      fb.u = *(const uint4*)&w1b[o * 64 + k];
      accY[os] = __builtin_amdgcn_mfma_f32_16x16x32_bf16(fa.s, Bf[kh].s, accY[os], 0, 0, 0);
      accZ[os] = __builtin_amdgcn_mfma_f32_16x16x32_bf16(fb.s, Bf[kh].s, accZ[os], 0, 0, 0);
    }
  }

  // D -> LDS repack: ds[j][o] (stride 72), bf16 pairs along o.
  const int jl = wv * 16 + n;
  #pragma unroll
  for (int os = 0; os < 4; os++) {
    #pragma unroll
    for (int rp = 0; rp < 4; rp += 2) {
      const int o = os * 16 + q * 4 + rp;
      *(unsigned*)&dsY[jl * 72 + o] = packbf(accY[os][rp], accY[os][rp + 1]);
      *(unsigned*)&dsZ[jl * 72 + o] =
          packbf(accZ[os][rp] + bias[o], accZ[os][rp + 1] + bias[o + 1]);
    }
  }
  __syncthreads();

  // Coalesced NHWC store
  #pragma unroll
  for (int p = 0; p < 2; p++) {
    const int slot = t + 256 * p;
    const int j = slot >> 3, og = slot & 7;
    const size_t gidx = (((size_t)b * Wn + w) * Hn + h0 + j) * 64 + og * 8;
    *(uint4*)&Y[gidx] = *(const uint4*)&dsY[j * 72 + og * 8];
    *(uint4*)&Z[gidx] = *(const uint4*)&dsZ[j * 72 + og * 8];
  }
}

// ---- 9-shift fused MFMA: out = max_s( W2 @ relu(Y_s + Z + pe_s) ) + b2 (+ x) ----
// Round-1 memory structure (T14 double-buffer, 4 barriers) with the pe-weight
// registers (48 VGPRs) replaced by a precomputed lane-independent vs9 table in
// LDS: h[k] = y[k] + zc[k] + rsv*vs_s[k] (1 fma/element). Persistent regs drop
// ~112 -> ~64, enabling 3 blocks/CU (launch_bounds(256,3), budget ~170).
__global__ __launch_bounds__(256, 3) void shift_max_kernel(
    const ushort* __restrict__ Y, const ushort* __restrict__ Z,
    const float* __restrict__ r, const float* __restrict__ vs9,
    const float* __restrict__ pw0, const ushort* __restrict__ w2p,
    const float* __restrict__ b2,
    const float* __restrict__ xres, const int add_res,
    float* __restrict__ out) {
  __shared__ __align__(16) ushort ys[2][66 * 72];  // [buf][jj][k], jj = h0-1..h0+64
  __shared__ float rsh[3][68];
  __shared__ __align__(16) float vsl[9 * 64];
  const int blk = blockIdx.x;
  const int h0 = (blk & 15) * 64;
  const int w  = (blk >> 4) & 63;
  const int b  = blk >> 10;
  const int t  = threadIdx.x;
  const int lane = t & 63, wv = t >> 6;
  const int n = lane & 15, q = lane >> 4;
  const int jl = wv * 16 + n;  // this lane's B column (local j)

  // vs table -> LDS (576 floats = 144 float4)
  if (t < 144) ((float4*)vsl)[t] = ((const float4*)vs9)[t];
  // r halo
  for (int i = t; i < 3 * 66; i += 256) {
    const int wi = i / 66, jj = i - wi * 66;
    const int wsrc = (w + wi - 1 + 64) & 63;
    const int hsrc = (h0 + jj - 1 + 1024) & 1023;
    rsh[wi][jj] = r[(size_t)b * HWn + wsrc * Hn + hsrc];
  }
  // stage ys buf0 for sw=-1 (wsrc = w+1)
  {
    const int wsrc = (w + 1) & 63;
    #pragma unroll
    for (int p = 0; p < 3; p++) {
      const int slot = t + 256 * p;
      if (slot < 66 * 8) {
        const int jj = slot >> 3, kg = slot & 7;
        const int hsrc = (h0 + jj - 1 + 1024) & 1023;
        *(uint4*)&ys[0][jj * 72 + kg * 8] =
            *(const uint4*)&Y[(((size_t)b * Wn + wsrc) * Hn + hsrc) * 64 + kg * 8];
      }
    }
  }

  // w2 A-fragments from pre-packed bf16 table (L2-hot, 8 x uint4).
  Frag A[8];  // [os][kh]
  #pragma unroll
  for (int os = 0; os < 4; os++) {
    const int o = os * 16 + n;
    #pragma unroll
    for (int kh = 0; kh < 2; kh++)
      A[os * 2 + kh].u = *(const uint4*)&w2p[o * 64 + kh * 32 + q * 8];
  }

  // z row (direct global, coalesced) folded with center-r term:
  // zc[k] = z[k] - rc*pw0[k]  (pw0 read transiently, not kept)
  const float rc = r[(size_t)b * HWn + (size_t)w * Hn + h0 + jl];
  float zcA[8], zcB[8];
  {
    const size_t zbase = (((size_t)b * Wn + w) * Hn + h0 + jl) * 64;
    const uint4 z0 = *(const uint4*)&Z[zbase + q * 8];
    const uint4 z1 = *(const uint4*)&Z[zbase + 32 + q * 8];
    const float4 pwA0 = *(const float4*)&pw0[q * 8];
    const float4 pwA1 = *(const float4*)&pw0[q * 8 + 4];
    const float4 pwB0 = *(const float4*)&pw0[32 + q * 8];
    const float4 pwB1 = *(const float4*)&pw0[32 + q * 8 + 4];
    const float pwA[8] = {pwA0.x, pwA0.y, pwA0.z, pwA0.w, pwA1.x, pwA1.y, pwA1.z, pwA1.w};
    const float pwB[8] = {pwB0.x, pwB0.y, pwB0.z, pwB0.w, pwB1.x, pwB1.y, pwB1.z, pwB1.w};
    const unsigned zw0[4] = {z0.x, z0.y, z0.z, z0.w};
    const unsigned zw1[4] = {z1.x, z1.y, z1.z, z1.w};
    #pragma unroll
    for (int p = 0; p < 4; p++) {
      zcA[2 * p]     = bflo(zw0[p]) - rc * pwA[2 * p];
      zcA[2 * p + 1] = bfhi(zw0[p]) - rc * pwA[2 * p + 1];
      zcB[2 * p]     = bflo(zw1[p]) - rc * pwB[2 * p];
      zcB[2 * p + 1] = bfhi(zw1[p]) - rc * pwB[2 * p + 1];
    }
  }

  __syncthreads();  // vsl + rsh + ys[0] visible

  f32x4 om[4];
  #pragma unroll
  for (int os = 0; os < 4; os++) om[os] = (f32x4)(-INFINITY);

  int cur = 0;
  for (int sw = -1; sw <= 1; sw++) {
    const int isw = sw + 1;
    // T14 issue-early: next tile's global loads into registers
    uint4 g0, g1, g2;
    if (sw < 1) {
      const int wsrc = (w - (sw + 1) + 64) & 63;
      const size_t ybase = ((size_t)b * Wn + wsrc) * Hn;
      {
        const int jj = t >> 3, kg = t & 7;
        const int hsrc = (h0 + jj - 1 + 1024) & 1023;
        g0 = *(const uint4*)&Y[(ybase + hsrc) * 64 + kg * 8];
      }
      {
        const int slot = t + 256;
        const int jj = slot >> 3, kg = slot & 7;
        const int hsrc = (h0 + jj - 1 + 1024) & 1023;
        g1 = *(const uint4*)&Y[(ybase + hsrc) * 64 + kg * 8];
      }
      if (t + 512 < 66 * 8) {
        const int slot = t + 512;
        const int jj = slot >> 3, kg = slot & 7;
        const int hsrc = (h0 + jj - 1 + 1024) & 1023;
        g2 = *(const uint4*)&Y[(ybase + hsrc) * 64 + kg * 8];
      }
    }

    // 3 h-shifts, register-resident, no barriers
    #pragma unroll
    for (int sh = -1; sh <= 1; sh++) {
      const int ish = sh + 1;
      const float rsv = rsh[1 - sw][jl - sh + 1];
      const float* vrow = &vsl[(isw * 3 + ish) * 64];
      const float4 vA0 = *(const float4*)&vrow[q * 8];
      const float4 vA1 = *(const float4*)&vrow[q * 8 + 4];
      const float4 vB0 = *(const float4*)&vrow[32 + q * 8];
      const float4 vB1 = *(const float4*)&vrow[32 + q * 8 + 4];
      const float vsA[8] = {vA0.x, vA0.y, vA0.z, vA0.w, vA1.x, vA1.y, vA1.z, vA1.w};
      const float vsB[8] = {vB0.x, vB0.y, vB0.z, vB0.w, vB1.x, vB1.y, vB1.z, vB1.w};
      const int yrow = (jl - sh + 1) * 72;
      const uint4 y0 = *(const uint4*)&ys[cur][yrow + q * 8];
      const uint4 y1 = *(const uint4*)&ys[cur][yrow + 32 + q * 8];
      const unsigned yw0[4] = {y0.x, y0.y, y0.z, y0.w};
      const unsigned yw1[4] = {y1.x, y1.y, y1.z, y1.w};
      unsigned hw0[4], hw1[4];
      #pragma unroll
      for (int p = 0; p < 4; p++) {
        const float hA0 = fmaf(rsv, vsA[2 * p],     bflo(yw0[p]) + zcA[2 * p]);
        const float hA1 = fmaf(rsv, vsA[2 * p + 1], bfhi(yw0[p]) + zcA[2 * p + 1]);
        hw0[p] = packbf(fmaxf(hA0, 0.f), fmaxf(hA1, 0.f));
        const float hB0 = fmaf(rsv, vsB[2 * p],     bflo(yw1[p]) + zcB[2 * p]);
        const float hB1 = fmaf(rsv, vsB[2 * p + 1], bfhi(yw1[p]) + zcB[2 * p + 1]);
        hw1[p] = packbf(fmaxf(hB0, 0.f), fmaxf(hB1, 0.f));
      }
      Frag Bf0, Bf1;
      Bf0.u = make_uint4(hw0[0], hw0[1], hw0[2], hw0[3]);
      Bf1.u = make_uint4(hw1[0], hw1[1], hw1[2], hw1[3]);
      #pragma unroll
      for (int os = 0; os < 4; os++) {
        f32x4 acc = (f32x4)0.f;
        acc = __builtin_amdgcn_mfma_f32_16x16x32_bf16(A[os * 2].s, Bf0.s, acc, 0, 0, 0);
        acc = __builtin_amdgcn_mfma_f32_16x16x32_bf16(A[os * 2 + 1].s, Bf1.s, acc, 0, 0, 0);
        #pragma unroll
        for (int e = 0; e < 4; e++) om[os][e] = fmaxf(om[os][e], acc[e]);
      }
    }

    // T14 write-late: park the prefetched tile in the other buffer
    if (sw < 1) {
      {
        const int jj = t >> 3, kg = t & 7;
        *(uint4*)&ys[cur ^ 1][jj * 72 + kg * 8] = g0;
      }
      {
        const int slot = t + 256;
        const int jj = slot >> 3, kg = slot & 7;
        *(uint4*)&ys[cur ^ 1][jj * 72 + kg * 8] = g1;
      }
      if (t + 512 < 66 * 8) {
        const int slot = t + 512;
        const int jj = slot >> 3, kg = slot & 7;
        *(uint4*)&ys[cur ^ 1][jj * 72 + kg * 8] = g2;
      }
    }
    __syncthreads();  // staging complete AND all readers of ys[cur] done
    cur ^= 1;
  }

  // epilogue: D layout col=lane&15 (j), row=q*4+e (o)
  const int jgl = h0 + jl;
  #pragma unroll
  for (int os = 0; os < 4; os++) {
    #pragma unroll
    for (int e = 0; e < 4; e++) {
      const int o = os * 16 + q * 4 + e;
      const size_t idx = ((size_t)b * Cn + o) * HWn + (size_t)w * Hn + jgl;
      float v = om[os][e] + b2[o];
      if (add_res) v += xres[idx];
      out[idx] = v;
    }
  }
}

}  // namespace

extern "C" void kernel_launch(void* const* d_in, const int* in_sizes, int n_in,
                              void* d_out, int out_size, void* d_ws, size_t ws_size,
                              hipStream_t stream) {
  const float* x    = (const float*)d_in[0];
  const float* r    = (const float*)d_in[1];
  const float* n1w  = (const float*)d_in[2];
  const float* n1b  = (const float*)d_in[3];
  const float* c1w1 = (const float*)d_in[4];
  const float* c1b1 = (const float*)d_in[5];
  const float* c1w2 = (const float*)d_in[6];
  const float* c1b2 = (const float*)d_in[7];
  const float* n2w  = (const float*)d_in[8];
  const float* n2b  = (const float*)d_in[9];
  const float* c2w1 = (const float*)d_in[10];
  const float* c2b1 = (const float*)d_in[11];
  const float* c2w2 = (const float*)d_in[12];
  const float* c2b2 = (const float*)d_in[13];
  float* out = (float*)d_out;

  // ws: [partial 256f][stats 256f][vs9 576f][pw0 64f][pad to 8192B]
  //     [Y bf16 32MiB][Z bf16 32MiB][w1a 8K][w1b 8K][w2p 8K]
  float* partial = (float*)d_ws;
  float* statsf  = partial + 256;
  float* vs9     = partial + 512;
  float* pw0     = partial + 1088;
  ushort* Ybf = (ushort*)((char*)d_ws + 8192);
  ushort* Zbf = Ybf + (size_t)Bn * Wn * Hn * 64;
  ushort* w1a = Zbf + (size_t)Bn * Wn * Hn * 64;
  ushort* w1b = w1a + 64 * 64;
  ushort* w2p = w1b + 64 * 64;

  // ---- block 1 ----
  hipMemsetAsync(partial, 0, 256 * sizeof(float), stream);
  gn_partial_kernel<<<2048, 256, 0, stream>>>(x, partial);
  gn_final_kernel<<<1, 128, 0, stream>>>(partial, statsf);
  pack_weights_kernel<<<1, 256, 0, stream>>>(c1w1, c1w2, w1a, w1b, w2p, vs9, pw0);
  dual_gemm_kernel<<<4096, 256, 0, stream>>>(x, statsf, n1w, n1b, w1a, w1b, c1b1, Ybf, Zbf);
  shift_max_kernel<<<4096, 256, 0, stream>>>(Ybf, Zbf, r, vs9, pw0, w2p, c1b2, x, 0, out);
  // ---- block 2 (edge_conv1 result parked in d_out) ----
  hipMemsetAsync(partial, 0, 256 * sizeof(float), stream);
  gn_partial_kernel<<<2048, 256, 0, stream>>>(out, partial);
  gn_final_kernel<<<1, 128, 0, stream>>>(partial, statsf);
  pack_weights_kernel<<<1, 256, 0, stream>>>(c2w1, c2w2, w1a, w1b, w2p, vs9, pw0);
  dual_gemm_kernel<<<4096, 256, 0, stream>>>(out, statsf, n2w, n2b, w1a, w1b, c2b1, Ybf, Zbf);
  shift_max_kernel<<<4096, 256, 0, stream>>>(Ybf, Zbf, r, vs9, pw0, w2p, c2b2, x, 1, out);
}